// Round 1
// baseline (1335.896 us; speedup 1.0000x reference)
//
#include <hip/hip_runtime.h>
#include <hip/hip_bf16.h>

#define NN 100000
#define NE 1600000

// ---------------- adjacency build ----------------

__global__ void zero_i32(int* __restrict__ p, int n) {
    int i = blockIdx.x * blockDim.x + threadIdx.x;
    if (i < n) p[i] = 0;
}

__global__ void count_rows(const int* __restrict__ row, int* __restrict__ counts) {
    int e = blockIdx.x * blockDim.x + threadIdx.x;
    if (e < NE) atomicAdd(&counts[row[e]], 1);
}

// single-block chunked inclusive scan -> offsets (exclusive +1), cursor, dinv
__global__ __launch_bounds__(1024) void scan_build(const int* __restrict__ counts,
                                                   int* __restrict__ offsets,
                                                   int* __restrict__ cursor,
                                                   float* __restrict__ dinv) {
    __shared__ int sb[1024];
    int tid = threadIdx.x;
    int carry = 0;
    for (int base = 0; base < NN; base += 1024) {
        int i = base + tid;
        int v = (i < NN) ? counts[i] : 0;
        sb[tid] = v;
        __syncthreads();
        #pragma unroll
        for (int s = 1; s < 1024; s <<= 1) {
            int t = (tid >= s) ? sb[tid - s] : 0;
            __syncthreads();
            sb[tid] += t;
            __syncthreads();
        }
        int incl  = sb[tid];
        int total = sb[1023];
        __syncthreads();   // protect sb before next tile's write
        if (i < NN) {
            offsets[i + 1] = carry + incl;
            cursor[i]      = carry + incl - v;   // exclusive
            dinv[i]        = rsqrtf((float)(v + 1));  // +1 self loop; deg>=1 always
        }
        carry += total;
    }
    if (tid == 0) offsets[0] = 0;
}

__global__ void scatter_cols(const int* __restrict__ row, const int* __restrict__ col,
                             int* __restrict__ cursor, int* __restrict__ csr_col) {
    int e = blockIdx.x * blockDim.x + threadIdx.x;
    if (e < NE) {
        int pos = atomicAdd(&cursor[row[e]], 1);
        csr_col[pos] = col[e];
    }
}

// ---------------- dense GEMM: T[N,F] = X[N,128] @ W[128,F] ----------------
// 256 threads: CG=F/4 column groups x RS row-subgroups, 4 rows x 4 cols per thread.
// W staged in LDS (K-tiled, <=32KB); X rows read from global (broadcast across CG lanes).
template<int F>
__global__ __launch_bounds__(256) void gemm128(const float* __restrict__ X,
                                               const float* __restrict__ W,
                                               float* __restrict__ T) {
    constexpr int K  = 128;
    constexpr int CG = F / 4;          // 32 or 16
    constexpr int RS = 256 / CG;       // 8 or 16
    constexpr int TM = 4;
    constexpr int MB = RS * TM;        // 32 or 64
    constexpr int KT = 64;
    __shared__ float Ws[KT][F];

    int tid  = threadIdx.x;
    int cg   = tid % CG;
    int trs  = tid / CG;
    int row0 = blockIdx.x * MB + trs * TM;

    float acc[TM][4];
    #pragma unroll
    for (int i = 0; i < TM; ++i)
        #pragma unroll
        for (int j = 0; j < 4; ++j) acc[i][j] = 0.f;

    int rclamp[TM];
    #pragma unroll
    for (int i = 0; i < TM; ++i) {
        int r = row0 + i;
        rclamp[i] = (r < NN) ? r : (NN - 1);   // clamp: safe load, store is guarded
    }

    for (int k0 = 0; k0 < K; k0 += KT) {
        constexpr int LD = KT * F / (256 * 4);  // float4 per thread: 8 or 4
        const float4* Wg = (const float4*)(W + k0 * F);
        float4*       Wl = (float4*)&Ws[0][0];
        #pragma unroll
        for (int l = 0; l < LD; ++l) Wl[tid + l * 256] = Wg[tid + l * 256];
        __syncthreads();

        #pragma unroll
        for (int k = 0; k < KT; k += 4) {
            float4 bv[4];
            #pragma unroll
            for (int j = 0; j < 4; ++j) bv[j] = *(const float4*)&Ws[k + j][cg * 4];
            #pragma unroll
            for (int i = 0; i < TM; ++i) {
                float4 a = *(const float4*)&X[(size_t)rclamp[i] * K + k0 + k];
                const float av[4] = {a.x, a.y, a.z, a.w};
                #pragma unroll
                for (int j = 0; j < 4; ++j) {
                    acc[i][0] = fmaf(av[j], bv[j].x, acc[i][0]);
                    acc[i][1] = fmaf(av[j], bv[j].y, acc[i][1]);
                    acc[i][2] = fmaf(av[j], bv[j].z, acc[i][2]);
                    acc[i][3] = fmaf(av[j], bv[j].w, acc[i][3]);
                }
            }
        }
        __syncthreads();
    }

    #pragma unroll
    for (int i = 0; i < TM; ++i) {
        int r = row0 + i;
        if (r < NN) {
            float4 o = make_float4(acc[i][0], acc[i][1], acc[i][2], acc[i][3]);
            *(float4*)&T[(size_t)r * F + cg * 4] = o;
        }
    }
}

// ---------------- SpMM gather: out[r] = dinv[r]*(sum dinv[c]*T[c] + dinv[r]*T[r]) + b ----------------
template<int F, bool RELU>
__global__ __launch_bounds__(256) void spmm_gather(const float* __restrict__ T,
                                                   const int* __restrict__ offsets,
                                                   const int* __restrict__ csr_col,
                                                   const float* __restrict__ dinv,
                                                   const float* __restrict__ bias,
                                                   float* __restrict__ out) {
    constexpr int RPB = 256 / F;
    int f = threadIdx.x % F;
    int rs = threadIdx.x / F;
    int r = blockIdx.x * RPB + rs;
    if (r >= NN) return;

    float dr = dinv[r];
    int o0 = offsets[r], o1 = offsets[r + 1];
    float acc = dr * T[(size_t)r * F + f];   // self-loop (outer dr applied at end)
    for (int j = o0; j < o1; ++j) {
        int c = csr_col[j];
        acc = fmaf(dinv[c], T[(size_t)c * F + f], acc);
    }
    float v = fmaf(dr, acc, bias[f]);
    if (RELU) v = fmaxf(v, 0.f);
    out[(size_t)r * F + f] = v;
}

// ---------------- launch ----------------

extern "C" void kernel_launch(void* const* d_in, const int* in_sizes, int n_in,
                              void* d_out, int out_size, void* d_ws, size_t ws_size,
                              hipStream_t stream) {
    const float* x  = (const float*)d_in[0];
    const int*   ei = (const int*)d_in[1];
    const float* W0 = (const float*)d_in[2];
    const float* b0 = (const float*)d_in[3];
    const float* W1 = (const float*)d_in[4];
    const float* b1 = (const float*)d_in[5];
    const float* W2 = (const float*)d_in[6];
    const float* b2 = (const float*)d_in[7];
    float* out = (float*)d_out;

    const int* row = ei;
    const int* col = ei + NE;

    char* wsp = (char*)d_ws;
    auto alloc = [&](size_t bytes) {
        char* p = wsp;
        wsp += (bytes + 255) & ~(size_t)255;
        return p;
    };
    int*   counts  = (int*)alloc((size_t)NN * 4);
    int*   offsets = (int*)alloc((size_t)(NN + 1) * 4);
    int*   cursor  = (int*)alloc((size_t)NN * 4);
    float* dinv    = (float*)alloc((size_t)NN * 4);
    int*   csr_col = (int*)alloc((size_t)NE * 4);
    float* Tbuf    = (float*)alloc((size_t)NN * 128 * 4);
    float* Hbuf    = (float*)alloc((size_t)NN * 128 * 4);

    // adjacency build
    zero_i32<<<(NN + 255) / 256, 256, 0, stream>>>(counts, NN);
    count_rows<<<(NE + 255) / 256, 256, 0, stream>>>(row, counts);
    scan_build<<<1, 1024, 0, stream>>>(counts, offsets, cursor, dinv);
    scatter_cols<<<(NE + 255) / 256, 256, 0, stream>>>(row, col, cursor, csr_col);

    // layer 1: H = relu(A @ (x W0) + b0)
    gemm128<128><<<(NN + 31) / 32, 256, 0, stream>>>(x, W0, Tbuf);
    spmm_gather<128, true><<<(NN + 1) / 2, 256, 0, stream>>>(Tbuf, offsets, csr_col, dinv, b0, Hbuf);
    // layer 2
    gemm128<128><<<(NN + 31) / 32, 256, 0, stream>>>(Hbuf, W1, Tbuf);
    spmm_gather<128, true><<<(NN + 1) / 2, 256, 0, stream>>>(Tbuf, offsets, csr_col, dinv, b1, Hbuf);
    // layer 3 (no relu) -> d_out
    gemm128<64><<<(NN + 63) / 64, 256, 0, stream>>>(Hbuf, W2, Tbuf);
    spmm_gather<64, false><<<(NN + 3) / 4, 256, 0, stream>>>(Tbuf, offsets, csr_col, dinv, b2, out);
}

// Round 2
// 928.886 us; speedup vs baseline: 1.4382x; 1.4382x over previous
//
#include <hip/hip_runtime.h>
#include <hip/hip_bf16.h>

#define NN 100000
#define NE 1600000

// ---------------- adjacency build ----------------

__global__ void zero_i32(int* __restrict__ p, int n) {
    int i = blockIdx.x * blockDim.x + threadIdx.x;
    if (i < n) p[i] = 0;
}

__global__ void count_rows(const int* __restrict__ row, int* __restrict__ counts) {
    int e = blockIdx.x * blockDim.x + threadIdx.x;
    if (e < NE) atomicAdd(&counts[row[e]], 1);
}

// single-block chunked inclusive scan -> offsets (exclusive +1), cursor, dinv
__global__ __launch_bounds__(1024) void scan_build(const int* __restrict__ counts,
                                                   int* __restrict__ offsets,
                                                   int* __restrict__ cursor,
                                                   float* __restrict__ dinv) {
    __shared__ int sb[1024];
    int tid = threadIdx.x;
    int carry = 0;
    for (int base = 0; base < NN; base += 1024) {
        int i = base + tid;
        int v = (i < NN) ? counts[i] : 0;
        sb[tid] = v;
        __syncthreads();
        #pragma unroll
        for (int s = 1; s < 1024; s <<= 1) {
            int t = (tid >= s) ? sb[tid - s] : 0;
            __syncthreads();
            sb[tid] += t;
            __syncthreads();
        }
        int incl  = sb[tid];
        int total = sb[1023];
        __syncthreads();   // protect sb before next tile's write
        if (i < NN) {
            offsets[i + 1] = carry + incl;
            cursor[i]      = carry + incl - v;   // exclusive
            dinv[i]        = rsqrtf((float)(v + 1));  // +1 self loop; deg>=1 always
        }
        carry += total;
    }
    if (tid == 0) offsets[0] = 0;
}

__global__ void scatter_cols(const int* __restrict__ row, const int* __restrict__ col,
                             int* __restrict__ cursor, int* __restrict__ csr_col) {
    int e = blockIdx.x * blockDim.x + threadIdx.x;
    if (e < NE) {
        int pos = atomicAdd(&cursor[row[e]], 1);
        csr_col[pos] = col[e];
    }
}

// ---------------- dense GEMM: T[N,F] = dinv[r] * (X[N,128] @ W[128,F]) ----------------
// 256 threads: CG=F/4 column groups x RS row-subgroups, 4 rows x 4 cols per thread.
// W staged in LDS (K-tiled); X rows read from global (broadcast across CG lanes).
// Epilogue scales row r by dinv[r] so the SpMM inner loop is a pure gather+add.
template<int F>
__global__ __launch_bounds__(256) void gemm128(const float* __restrict__ X,
                                               const float* __restrict__ W,
                                               const float* __restrict__ dinv,
                                               float* __restrict__ T) {
    constexpr int K  = 128;
    constexpr int CG = F / 4;          // 32 or 16
    constexpr int RS = 256 / CG;       // 8 or 16
    constexpr int TM = 4;
    constexpr int MB = RS * TM;        // 32 or 64
    constexpr int KT = 64;
    __shared__ float Ws[KT][F];

    int tid  = threadIdx.x;
    int cg   = tid % CG;
    int trs  = tid / CG;
    int row0 = blockIdx.x * MB + trs * TM;

    float acc[TM][4];
    #pragma unroll
    for (int i = 0; i < TM; ++i)
        #pragma unroll
        for (int j = 0; j < 4; ++j) acc[i][j] = 0.f;

    int rclamp[TM];
    #pragma unroll
    for (int i = 0; i < TM; ++i) {
        int r = row0 + i;
        rclamp[i] = (r < NN) ? r : (NN - 1);   // clamp: safe load, store is guarded
    }

    for (int k0 = 0; k0 < K; k0 += KT) {
        constexpr int LD = KT * F / (256 * 4);  // float4 per thread: 8 or 4
        const float4* Wg = (const float4*)(W + k0 * F);
        float4*       Wl = (float4*)&Ws[0][0];
        #pragma unroll
        for (int l = 0; l < LD; ++l) Wl[tid + l * 256] = Wg[tid + l * 256];
        __syncthreads();

        #pragma unroll
        for (int k = 0; k < KT; k += 4) {
            float4 bv[4];
            #pragma unroll
            for (int j = 0; j < 4; ++j) bv[j] = *(const float4*)&Ws[k + j][cg * 4];
            #pragma unroll
            for (int i = 0; i < TM; ++i) {
                float4 a = *(const float4*)&X[(size_t)rclamp[i] * K + k0 + k];
                const float av[4] = {a.x, a.y, a.z, a.w};
                #pragma unroll
                for (int j = 0; j < 4; ++j) {
                    acc[i][0] = fmaf(av[j], bv[j].x, acc[i][0]);
                    acc[i][1] = fmaf(av[j], bv[j].y, acc[i][1]);
                    acc[i][2] = fmaf(av[j], bv[j].z, acc[i][2]);
                    acc[i][3] = fmaf(av[j], bv[j].w, acc[i][3]);
                }
            }
        }
        __syncthreads();
    }

    #pragma unroll
    for (int i = 0; i < TM; ++i) {
        int r = row0 + i;
        if (r < NN) {
            float dr = dinv[r];
            float4 o = make_float4(dr * acc[i][0], dr * acc[i][1],
                                   dr * acc[i][2], dr * acc[i][3]);
            *(float4*)&T[(size_t)r * F + cg * 4] = o;
        }
    }
}

// ---------------- SpMM gather: out[r] = dinv[r]*(sum_{c in nbr} T'[c] + T'[r]) + b ----------------
// T' is pre-scaled by dinv. float4 per lane, neighbor loop unrolled x4 with
// independent accumulators for memory-level parallelism.
template<int F, bool RELU>
__global__ __launch_bounds__(256) void spmm_gather(const float* __restrict__ T,
                                                   const int* __restrict__ offsets,
                                                   const int* __restrict__ csr_col,
                                                   const float* __restrict__ dinv,
                                                   const float* __restrict__ bias,
                                                   float* __restrict__ out) {
    constexpr int LPR = F / 4;          // lanes per row: 32 (F=128) or 16 (F=64)
    constexpr int RPB = 256 / LPR;      // rows per block: 8 or 16
    int lane = threadIdx.x % LPR;
    int rs   = threadIdx.x / LPR;
    int r    = blockIdx.x * RPB + rs;
    if (r >= NN) return;

    const float4* Tv = (const float4*)T;
    int o0 = offsets[r], o1 = offsets[r + 1];

    // self-loop: T'_r (already dinv[r]-scaled)
    float4 a0 = Tv[(size_t)r * LPR + lane];
    float4 a1 = make_float4(0.f, 0.f, 0.f, 0.f);
    float4 a2 = a1, a3 = a1;

    int j = o0;
    for (; j + 4 <= o1; j += 4) {
        int c0 = csr_col[j    ];
        int c1 = csr_col[j + 1];
        int c2 = csr_col[j + 2];
        int c3 = csr_col[j + 3];
        float4 v0 = Tv[(size_t)c0 * LPR + lane];
        float4 v1 = Tv[(size_t)c1 * LPR + lane];
        float4 v2 = Tv[(size_t)c2 * LPR + lane];
        float4 v3 = Tv[(size_t)c3 * LPR + lane];
        a0.x += v0.x; a0.y += v0.y; a0.z += v0.z; a0.w += v0.w;
        a1.x += v1.x; a1.y += v1.y; a1.z += v1.z; a1.w += v1.w;
        a2.x += v2.x; a2.y += v2.y; a2.z += v2.z; a2.w += v2.w;
        a3.x += v3.x; a3.y += v3.y; a3.z += v3.z; a3.w += v3.w;
    }
    for (; j < o1; ++j) {
        int c = csr_col[j];
        float4 v = Tv[(size_t)c * LPR + lane];
        a0.x += v.x; a0.y += v.y; a0.z += v.z; a0.w += v.w;
    }

    float sx = (a0.x + a1.x) + (a2.x + a3.x);
    float sy = (a0.y + a1.y) + (a2.y + a3.y);
    float sz = (a0.z + a1.z) + (a2.z + a3.z);
    float sw = (a0.w + a1.w) + (a2.w + a3.w);

    float dr = dinv[r];
    const float4 bv = *(const float4*)&bias[lane * 4];
    float4 o;
    o.x = fmaf(dr, sx, bv.x);
    o.y = fmaf(dr, sy, bv.y);
    o.z = fmaf(dr, sz, bv.z);
    o.w = fmaf(dr, sw, bv.w);
    if (RELU) {
        o.x = fmaxf(o.x, 0.f); o.y = fmaxf(o.y, 0.f);
        o.z = fmaxf(o.z, 0.f); o.w = fmaxf(o.w, 0.f);
    }
    ((float4*)out)[(size_t)r * LPR + lane] = o;
}

// ---------------- launch ----------------

extern "C" void kernel_launch(void* const* d_in, const int* in_sizes, int n_in,
                              void* d_out, int out_size, void* d_ws, size_t ws_size,
                              hipStream_t stream) {
    const float* x  = (const float*)d_in[0];
    const int*   ei = (const int*)d_in[1];
    const float* W0 = (const float*)d_in[2];
    const float* b0 = (const float*)d_in[3];
    const float* W1 = (const float*)d_in[4];
    const float* b1 = (const float*)d_in[5];
    const float* W2 = (const float*)d_in[6];
    const float* b2 = (const float*)d_in[7];
    float* out = (float*)d_out;

    const int* row = ei;
    const int* col = ei + NE;

    char* wsp = (char*)d_ws;
    auto alloc = [&](size_t bytes) {
        char* p = wsp;
        wsp += (bytes + 255) & ~(size_t)255;
        return p;
    };
    int*   counts  = (int*)alloc((size_t)NN * 4);
    int*   offsets = (int*)alloc((size_t)(NN + 1) * 4);
    int*   cursor  = (int*)alloc((size_t)NN * 4);
    float* dinv    = (float*)alloc((size_t)NN * 4);
    int*   csr_col = (int*)alloc((size_t)NE * 4);
    float* Tbuf    = (float*)alloc((size_t)NN * 128 * 4);
    float* Hbuf    = (float*)alloc((size_t)NN * 128 * 4);

    // adjacency build
    zero_i32<<<(NN + 255) / 256, 256, 0, stream>>>(counts, NN);
    count_rows<<<(NE + 255) / 256, 256, 0, stream>>>(row, counts);
    scan_build<<<1, 1024, 0, stream>>>(counts, offsets, cursor, dinv);
    scatter_cols<<<(NE + 255) / 256, 256, 0, stream>>>(row, col, cursor, csr_col);

    // layer 1: H = relu(A @ (x W0) + b0)
    gemm128<128><<<(NN + 31) / 32, 256, 0, stream>>>(x, W0, dinv, Tbuf);
    spmm_gather<128, true><<<(NN + 7) / 8, 256, 0, stream>>>(Tbuf, offsets, csr_col, dinv, b0, Hbuf);
    // layer 2
    gemm128<128><<<(NN + 31) / 32, 256, 0, stream>>>(Hbuf, W1, dinv, Tbuf);
    spmm_gather<128, true><<<(NN + 7) / 8, 256, 0, stream>>>(Tbuf, offsets, csr_col, dinv, b1, Hbuf);
    // layer 3 (no relu) -> d_out
    gemm128<64><<<(NN + 63) / 64, 256, 0, stream>>>(Hbuf, W2, dinv, Tbuf);
    spmm_gather<64, false><<<(NN + 15) / 16, 256, 0, stream>>>(Tbuf, offsets, csr_col, dinv, b2, out);
}

// Round 3
// 750.662 us; speedup vs baseline: 1.7796x; 1.2374x over previous
//
#include <hip/hip_runtime.h>
#include <hip/hip_bf16.h>

#define NN 100000
#define NE 1600000
#define NB ((NN + 1023) / 1024)   // 98 scan blocks

// ---------------- adjacency build ----------------

__global__ void zero_i32(int* __restrict__ p, int n) {
    int i = blockIdx.x * blockDim.x + threadIdx.x;
    if (i < n) p[i] = 0;
}

__global__ void count_rows(const int* __restrict__ row, int* __restrict__ counts) {
    int e = blockIdx.x * blockDim.x + threadIdx.x;
    if (e < NE) atomicAdd(&counts[row[e]], 1);
}

// phase A: per-block inclusive scan of a 1024-tile; write tile scan + block sum
__global__ __launch_bounds__(1024) void scan_a(const int* __restrict__ counts,
                                               int* __restrict__ incl,
                                               int* __restrict__ bsums) {
    __shared__ int sb[1024];
    int tid = threadIdx.x;
    int i = blockIdx.x * 1024 + tid;
    int v = (i < NN) ? counts[i] : 0;
    sb[tid] = v;
    __syncthreads();
    #pragma unroll
    for (int s = 1; s < 1024; s <<= 1) {
        int t = (tid >= s) ? sb[tid - s] : 0;
        __syncthreads();
        sb[tid] += t;
        __syncthreads();
    }
    if (i < NN) incl[i] = sb[tid];
    if (tid == 1023) bsums[blockIdx.x] = sb[1023];
}

// phase C: each block reduces bsums[0..bid) for its prefix, then emits
// offsets (exclusive+1), cursor, dinv.
__global__ __launch_bounds__(1024) void scan_c(const int* __restrict__ counts,
                                               const int* __restrict__ incl,
                                               const int* __restrict__ bsums,
                                               int* __restrict__ offsets,
                                               int* __restrict__ cursor,
                                               float* __restrict__ dinv) {
    __shared__ int red[128];
    int tid = threadIdx.x;
    int b = blockIdx.x;
    if (tid < 128) red[tid] = (tid < b) ? bsums[tid] : 0;   // b <= 98 < 128
    __syncthreads();
    if (tid < 64) red[tid] += red[tid + 64];
    __syncthreads();
    if (tid < 32) red[tid] += red[tid + 32];
    __syncthreads();
    if (tid < 16) red[tid] += red[tid + 16];
    __syncthreads();
    if (tid < 8) red[tid] += red[tid + 8];
    __syncthreads();
    if (tid < 4) red[tid] += red[tid + 4];
    __syncthreads();
    if (tid < 2) red[tid] += red[tid + 2];
    __syncthreads();
    if (tid < 1) red[tid] += red[tid + 1];
    __syncthreads();
    int pre = red[0];

    int i = b * 1024 + tid;
    if (i < NN) {
        int v = counts[i];
        int inc = pre + incl[i];
        offsets[i + 1] = inc;
        cursor[i]      = inc - v;                 // exclusive
        dinv[i]        = rsqrtf((float)(v + 1));  // +1 self loop
    }
    if (b == 0 && tid == 0) offsets[0] = 0;
}

__global__ void scatter_cols(const int* __restrict__ row, const int* __restrict__ col,
                             int* __restrict__ cursor, int* __restrict__ csr_col) {
    int e = blockIdx.x * blockDim.x + threadIdx.x;
    if (e < NE) {
        int pos = atomicAdd(&cursor[row[e]], 1);
        csr_col[pos] = col[e];
    }
}

// ---------------- dense GEMM: T[N,F] = dinv[r] * (X[N,128] @ W[128,F]) ----------------
template<int F>
__global__ __launch_bounds__(256) void gemm128(const float* __restrict__ X,
                                               const float* __restrict__ W,
                                               const float* __restrict__ dinv,
                                               float* __restrict__ T) {
    constexpr int K  = 128;
    constexpr int CG = F / 4;          // 32 or 16
    constexpr int RS = 256 / CG;       // 8 or 16
    constexpr int TM = 4;
    constexpr int MB = RS * TM;        // 32 or 64
    constexpr int KT = 64;
    __shared__ float Ws[KT][F];

    int tid  = threadIdx.x;
    int cg   = tid % CG;
    int trs  = tid / CG;
    int row0 = blockIdx.x * MB + trs * TM;

    float acc[TM][4];
    #pragma unroll
    for (int i = 0; i < TM; ++i)
        #pragma unroll
        for (int j = 0; j < 4; ++j) acc[i][j] = 0.f;

    int rclamp[TM];
    #pragma unroll
    for (int i = 0; i < TM; ++i) {
        int r = row0 + i;
        rclamp[i] = (r < NN) ? r : (NN - 1);   // clamp: safe load, store is guarded
    }

    for (int k0 = 0; k0 < K; k0 += KT) {
        constexpr int LD = KT * F / (256 * 4);  // float4 per thread: 8 or 4
        const float4* Wg = (const float4*)(W + k0 * F);
        float4*       Wl = (float4*)&Ws[0][0];
        #pragma unroll
        for (int l = 0; l < LD; ++l) Wl[tid + l * 256] = Wg[tid + l * 256];
        __syncthreads();

        #pragma unroll
        for (int k = 0; k < KT; k += 4) {
            float4 bv[4];
            #pragma unroll
            for (int j = 0; j < 4; ++j) bv[j] = *(const float4*)&Ws[k + j][cg * 4];
            #pragma unroll
            for (int i = 0; i < TM; ++i) {
                float4 a = *(const float4*)&X[(size_t)rclamp[i] * K + k0 + k];
                const float av[4] = {a.x, a.y, a.z, a.w};
                #pragma unroll
                for (int j = 0; j < 4; ++j) {
                    acc[i][0] = fmaf(av[j], bv[j].x, acc[i][0]);
                    acc[i][1] = fmaf(av[j], bv[j].y, acc[i][1]);
                    acc[i][2] = fmaf(av[j], bv[j].z, acc[i][2]);
                    acc[i][3] = fmaf(av[j], bv[j].w, acc[i][3]);
                }
            }
        }
        __syncthreads();
    }

    #pragma unroll
    for (int i = 0; i < TM; ++i) {
        int r = row0 + i;
        if (r < NN) {
            float dr = dinv[r];
            float4 o = make_float4(dr * acc[i][0], dr * acc[i][1],
                                   dr * acc[i][2], dr * acc[i][3]);
            *(float4*)&T[(size_t)r * F + cg * 4] = o;
        }
    }
}

// ---------------- SpMM gather: out[r] = dinv[r]*(sum_{c in nbr} T'[c] + T'[r]) + b ----------------
template<int F, bool RELU>
__global__ __launch_bounds__(256) void spmm_gather(const float* __restrict__ T,
                                                   const int* __restrict__ offsets,
                                                   const int* __restrict__ csr_col,
                                                   const float* __restrict__ dinv,
                                                   const float* __restrict__ bias,
                                                   float* __restrict__ out) {
    constexpr int LPR = F / 4;          // lanes per row: 32 (F=128) or 16 (F=64)
    constexpr int RPB = 256 / LPR;      // rows per block: 8 or 16
    int lane = threadIdx.x % LPR;
    int rs   = threadIdx.x / LPR;
    int r    = blockIdx.x * RPB + rs;
    if (r >= NN) return;

    const float4* Tv = (const float4*)T;
    int o0 = offsets[r], o1 = offsets[r + 1];

    // self-loop: T'_r (already dinv[r]-scaled)
    float4 a0 = Tv[(size_t)r * LPR + lane];
    float4 a1 = make_float4(0.f, 0.f, 0.f, 0.f);
    float4 a2 = a1, a3 = a1;

    int j = o0;
    for (; j + 4 <= o1; j += 4) {
        int c0 = csr_col[j    ];
        int c1 = csr_col[j + 1];
        int c2 = csr_col[j + 2];
        int c3 = csr_col[j + 3];
        float4 v0 = Tv[(size_t)c0 * LPR + lane];
        float4 v1 = Tv[(size_t)c1 * LPR + lane];
        float4 v2 = Tv[(size_t)c2 * LPR + lane];
        float4 v3 = Tv[(size_t)c3 * LPR + lane];
        a0.x += v0.x; a0.y += v0.y; a0.z += v0.z; a0.w += v0.w;
        a1.x += v1.x; a1.y += v1.y; a1.z += v1.z; a1.w += v1.w;
        a2.x += v2.x; a2.y += v2.y; a2.z += v2.z; a2.w += v2.w;
        a3.x += v3.x; a3.y += v3.y; a3.z += v3.z; a3.w += v3.w;
    }
    for (; j < o1; ++j) {
        int c = csr_col[j];
        float4 v = Tv[(size_t)c * LPR + lane];
        a0.x += v.x; a0.y += v.y; a0.z += v.z; a0.w += v.w;
    }

    float sx = (a0.x + a1.x) + (a2.x + a3.x);
    float sy = (a0.y + a1.y) + (a2.y + a3.y);
    float sz = (a0.z + a1.z) + (a2.z + a3.z);
    float sw = (a0.w + a1.w) + (a2.w + a3.w);

    float dr = dinv[r];
    const float4 bv = *(const float4*)&bias[lane * 4];
    float4 o;
    o.x = fmaf(dr, sx, bv.x);
    o.y = fmaf(dr, sy, bv.y);
    o.z = fmaf(dr, sz, bv.z);
    o.w = fmaf(dr, sw, bv.w);
    if (RELU) {
        o.x = fmaxf(o.x, 0.f); o.y = fmaxf(o.y, 0.f);
        o.z = fmaxf(o.z, 0.f); o.w = fmaxf(o.w, 0.f);
    }
    ((float4*)out)[(size_t)r * LPR + lane] = o;
}

// ---------------- launch ----------------

extern "C" void kernel_launch(void* const* d_in, const int* in_sizes, int n_in,
                              void* d_out, int out_size, void* d_ws, size_t ws_size,
                              hipStream_t stream) {
    const float* x  = (const float*)d_in[0];
    const int*   ei = (const int*)d_in[1];
    const float* W0 = (const float*)d_in[2];
    const float* b0 = (const float*)d_in[3];
    const float* W1 = (const float*)d_in[4];
    const float* b1 = (const float*)d_in[5];
    const float* W2 = (const float*)d_in[6];
    const float* b2 = (const float*)d_in[7];
    float* out = (float*)d_out;

    const int* row = ei;
    const int* col = ei + NE;

    char* wsp = (char*)d_ws;
    auto alloc = [&](size_t bytes) {
        char* p = wsp;
        wsp += (bytes + 255) & ~(size_t)255;
        return p;
    };
    int*   counts  = (int*)alloc((size_t)NN * 4);
    int*   incl    = (int*)alloc((size_t)NN * 4);
    int*   bsums   = (int*)alloc((size_t)NB * 4);
    int*   offsets = (int*)alloc((size_t)(NN + 1) * 4);
    int*   cursor  = (int*)alloc((size_t)NN * 4);
    float* dinv    = (float*)alloc((size_t)NN * 4);
    int*   csr_col = (int*)alloc((size_t)NE * 4);
    float* Tbuf    = (float*)alloc((size_t)NN * 128 * 4);
    float* Hbuf    = (float*)alloc((size_t)NN * 128 * 4);

    // adjacency build
    zero_i32<<<(NN + 255) / 256, 256, 0, stream>>>(counts, NN);
    count_rows<<<(NE + 255) / 256, 256, 0, stream>>>(row, counts);
    scan_a<<<NB, 1024, 0, stream>>>(counts, incl, bsums);
    scan_c<<<NB, 1024, 0, stream>>>(counts, incl, bsums, offsets, cursor, dinv);
    scatter_cols<<<(NE + 255) / 256, 256, 0, stream>>>(row, col, cursor, csr_col);

    // layer 1: H = relu(A @ (x W0) + b0)
    gemm128<128><<<(NN + 31) / 32, 256, 0, stream>>>(x, W0, dinv, Tbuf);
    spmm_gather<128, true><<<(NN + 7) / 8, 256, 0, stream>>>(Tbuf, offsets, csr_col, dinv, b0, Hbuf);
    // layer 2
    gemm128<128><<<(NN + 31) / 32, 256, 0, stream>>>(Hbuf, W1, dinv, Tbuf);
    spmm_gather<128, true><<<(NN + 7) / 8, 256, 0, stream>>>(Tbuf, offsets, csr_col, dinv, b1, Hbuf);
    // layer 3 (no relu) -> d_out
    gemm128<64><<<(NN + 63) / 64, 256, 0, stream>>>(Hbuf, W2, dinv, Tbuf);
    spmm_gather<64, false><<<(NN + 15) / 16, 256, 0, stream>>>(Tbuf, offsets, csr_col, dinv, b2, out);
}

// Round 4
// 735.789 us; speedup vs baseline: 1.8156x; 1.0202x over previous
//
#include <hip/hip_runtime.h>
#include <hip/hip_bf16.h>

#define NN 100000
#define NE 1600000
#define NB ((NN + 1023) / 1024)   // 98 scan blocks
#define SB 1024                    // scatter blocks inside fused kernel

// ---------------- adjacency build ----------------

__global__ void zero_i32(int* __restrict__ p, int n) {
    int i = blockIdx.x * blockDim.x + threadIdx.x;
    if (i < n) p[i] = 0;
}

__global__ void count_rows(const int* __restrict__ row, int* __restrict__ counts) {
    int e = blockIdx.x * blockDim.x + threadIdx.x;
    if (e < NE) atomicAdd(&counts[row[e]], 1);
}

// phase A: per-block inclusive scan of a 1024-tile; write tile scan + block sum
__global__ __launch_bounds__(1024) void scan_a(const int* __restrict__ counts,
                                               int* __restrict__ incl,
                                               int* __restrict__ bsums) {
    __shared__ int sb[1024];
    int tid = threadIdx.x;
    int i = blockIdx.x * 1024 + tid;
    int v = (i < NN) ? counts[i] : 0;
    sb[tid] = v;
    __syncthreads();
    #pragma unroll
    for (int s = 1; s < 1024; s <<= 1) {
        int t = (tid >= s) ? sb[tid - s] : 0;
        __syncthreads();
        sb[tid] += t;
        __syncthreads();
    }
    if (i < NN) incl[i] = sb[tid];
    if (tid == 1023) bsums[blockIdx.x] = sb[1023];
}

// phase C: each block reduces bsums[0..bid) for its prefix, then emits
// offsets (exclusive+1), cursor, dinv.
__global__ __launch_bounds__(1024) void scan_c(const int* __restrict__ counts,
                                               const int* __restrict__ incl,
                                               const int* __restrict__ bsums,
                                               int* __restrict__ offsets,
                                               int* __restrict__ cursor,
                                               float* __restrict__ dinv) {
    __shared__ int red[128];
    int tid = threadIdx.x;
    int b = blockIdx.x;
    if (tid < 128) red[tid] = (tid < b) ? bsums[tid] : 0;   // b <= 98 < 128
    __syncthreads();
    if (tid < 64) red[tid] += red[tid + 64];
    __syncthreads();
    if (tid < 32) red[tid] += red[tid + 32];
    __syncthreads();
    if (tid < 16) red[tid] += red[tid + 16];
    __syncthreads();
    if (tid < 8) red[tid] += red[tid + 8];
    __syncthreads();
    if (tid < 4) red[tid] += red[tid + 4];
    __syncthreads();
    if (tid < 2) red[tid] += red[tid + 2];
    __syncthreads();
    if (tid < 1) red[tid] += red[tid + 1];
    __syncthreads();
    int pre = red[0];

    int i = b * 1024 + tid;
    if (i < NN) {
        int v = counts[i];
        int inc = pre + incl[i];
        offsets[i + 1] = inc;
        cursor[i]      = inc - v;                 // exclusive
        dinv[i]        = rsqrtf((float)(v + 1));  // +1 self loop
    }
    if (b == 0 && tid == 0) offsets[0] = 0;
}

// ---------------- dense GEMM body: T[N,F] = [dinv[r] *] (X[N,128] @ W[128,F]) ----------------
template<int F, bool SCALE>
__device__ __forceinline__ void gemm_body(const float* __restrict__ X,
                                          const float* __restrict__ W,
                                          const float* __restrict__ dinv,
                                          float* __restrict__ T,
                                          float* __restrict__ ws_raw,
                                          int bid) {
    constexpr int K  = 128;
    constexpr int CG = F / 4;          // 32 or 16
    constexpr int RS = 256 / CG;       // 8 or 16
    constexpr int TM = 4;
    constexpr int MB = RS * TM;        // 32 or 64
    constexpr int KT = 64;
    float (*Ws)[F] = (float (*)[F])ws_raw;

    int tid  = threadIdx.x;
    int cg   = tid % CG;
    int trs  = tid / CG;
    int row0 = bid * MB + trs * TM;

    float acc[TM][4];
    #pragma unroll
    for (int i = 0; i < TM; ++i)
        #pragma unroll
        for (int j = 0; j < 4; ++j) acc[i][j] = 0.f;

    int rclamp[TM];
    #pragma unroll
    for (int i = 0; i < TM; ++i) {
        int r = row0 + i;
        rclamp[i] = (r < NN) ? r : (NN - 1);   // clamp: safe load, store is guarded
    }

    for (int k0 = 0; k0 < K; k0 += KT) {
        constexpr int LD = KT * F / (256 * 4);  // float4 per thread: 8 or 4
        const float4* Wg = (const float4*)(W + k0 * F);
        float4*       Wl = (float4*)&Ws[0][0];
        #pragma unroll
        for (int l = 0; l < LD; ++l) Wl[tid + l * 256] = Wg[tid + l * 256];
        __syncthreads();

        #pragma unroll
        for (int k = 0; k < KT; k += 4) {
            float4 bv[4];
            #pragma unroll
            for (int j = 0; j < 4; ++j) bv[j] = *(const float4*)&Ws[k + j][cg * 4];
            #pragma unroll
            for (int i = 0; i < TM; ++i) {
                float4 a = *(const float4*)&X[(size_t)rclamp[i] * K + k0 + k];
                const float av[4] = {a.x, a.y, a.z, a.w};
                #pragma unroll
                for (int j = 0; j < 4; ++j) {
                    acc[i][0] = fmaf(av[j], bv[j].x, acc[i][0]);
                    acc[i][1] = fmaf(av[j], bv[j].y, acc[i][1]);
                    acc[i][2] = fmaf(av[j], bv[j].z, acc[i][2]);
                    acc[i][3] = fmaf(av[j], bv[j].w, acc[i][3]);
                }
            }
        }
        __syncthreads();
    }

    #pragma unroll
    for (int i = 0; i < TM; ++i) {
        int r = row0 + i;
        if (r < NN) {
            float dr = SCALE ? dinv[r] : 1.0f;
            float4 o = make_float4(dr * acc[i][0], dr * acc[i][1],
                                   dr * acc[i][2], dr * acc[i][3]);
            *(float4*)&T[(size_t)r * F + cg * 4] = o;
        }
    }
}

template<int F>
__global__ __launch_bounds__(256) void gemm128(const float* __restrict__ X,
                                               const float* __restrict__ W,
                                               const float* __restrict__ dinv,
                                               float* __restrict__ T) {
    __shared__ float Ws[64 * F];
    gemm_body<F, true>(X, W, dinv, T, Ws, blockIdx.x);
}

// ---------------- fused: CSR scatter (write-bound) || layer-1 GEMM raw (VALU-bound) ----------------
__global__ __launch_bounds__(256) void fused_scatter_gemm(const int* __restrict__ row,
                                                          const int* __restrict__ col,
                                                          int* __restrict__ cursor,
                                                          int* __restrict__ csr_col,
                                                          const float* __restrict__ X,
                                                          const float* __restrict__ W0,
                                                          float* __restrict__ Traw) {
    __shared__ float Ws[64 * 128];
    if (blockIdx.x < SB) {
        // grid-stride scatter: ~6 edges/thread, independent atomic chains in flight
        int e = blockIdx.x * 256 + threadIdx.x;
        const int stride = SB * 256;
        for (; e < NE; e += stride) {
            int r = row[e];
            int c = col[e];
            int pos = atomicAdd(&cursor[r], 1);
            csr_col[pos] = c;
        }
    } else {
        gemm_body<128, false>(X, W0, nullptr, Traw, Ws, blockIdx.x - SB);
    }
}

// ---------------- SpMM gather ----------------
// PRESCALED: T already carries dinv (from GEMM epilogue). Otherwise apply dinv[c]
// per edge (broadcast dword across the row-group lanes).
// out[r] = dinv[r]*(sum_{c in nbr} dinv[c]*T[c] + dinv[r]*T[r]) + b
template<int F, bool RELU, bool PRESCALED>
__global__ __launch_bounds__(256) void spmm_gather(const float* __restrict__ T,
                                                   const int* __restrict__ offsets,
                                                   const int* __restrict__ csr_col,
                                                   const float* __restrict__ dinv,
                                                   const float* __restrict__ bias,
                                                   float* __restrict__ out) {
    constexpr int LPR = F / 4;          // lanes per row: 32 (F=128) or 16 (F=64)
    constexpr int RPB = 256 / LPR;      // rows per block: 8 or 16
    int lane = threadIdx.x % LPR;
    int rs   = threadIdx.x / LPR;
    int r    = blockIdx.x * RPB + rs;
    if (r >= NN) return;

    const float4* Tv = (const float4*)T;
    int o0 = offsets[r], o1 = offsets[r + 1];

    float dr = dinv[r];
    // self-loop term
    float4 tself = Tv[(size_t)r * LPR + lane];
    float sscale = PRESCALED ? 1.0f : dr;
    float4 a0 = make_float4(sscale * tself.x, sscale * tself.y,
                            sscale * tself.z, sscale * tself.w);
    float4 a1 = make_float4(0.f, 0.f, 0.f, 0.f);
    float4 a2 = a1, a3 = a1;

    int j = o0;
    for (; j + 4 <= o1; j += 4) {
        int c0 = csr_col[j    ];
        int c1 = csr_col[j + 1];
        int c2 = csr_col[j + 2];
        int c3 = csr_col[j + 3];
        float4 v0 = Tv[(size_t)c0 * LPR + lane];
        float4 v1 = Tv[(size_t)c1 * LPR + lane];
        float4 v2 = Tv[(size_t)c2 * LPR + lane];
        float4 v3 = Tv[(size_t)c3 * LPR + lane];
        if (PRESCALED) {
            a0.x += v0.x; a0.y += v0.y; a0.z += v0.z; a0.w += v0.w;
            a1.x += v1.x; a1.y += v1.y; a1.z += v1.z; a1.w += v1.w;
            a2.x += v2.x; a2.y += v2.y; a2.z += v2.z; a2.w += v2.w;
            a3.x += v3.x; a3.y += v3.y; a3.z += v3.z; a3.w += v3.w;
        } else {
            float d0 = dinv[c0], d1 = dinv[c1], d2 = dinv[c2], d3 = dinv[c3];
            a0.x = fmaf(d0, v0.x, a0.x); a0.y = fmaf(d0, v0.y, a0.y);
            a0.z = fmaf(d0, v0.z, a0.z); a0.w = fmaf(d0, v0.w, a0.w);
            a1.x = fmaf(d1, v1.x, a1.x); a1.y = fmaf(d1, v1.y, a1.y);
            a1.z = fmaf(d1, v1.z, a1.z); a1.w = fmaf(d1, v1.w, a1.w);
            a2.x = fmaf(d2, v2.x, a2.x); a2.y = fmaf(d2, v2.y, a2.y);
            a2.z = fmaf(d2, v2.z, a2.z); a2.w = fmaf(d2, v2.w, a2.w);
            a3.x = fmaf(d3, v3.x, a3.x); a3.y = fmaf(d3, v3.y, a3.y);
            a3.z = fmaf(d3, v3.z, a3.z); a3.w = fmaf(d3, v3.w, a3.w);
        }
    }
    for (; j < o1; ++j) {
        int c = csr_col[j];
        float4 v = Tv[(size_t)c * LPR + lane];
        float d = PRESCALED ? 1.0f : dinv[c];
        a0.x = fmaf(d, v.x, a0.x); a0.y = fmaf(d, v.y, a0.y);
        a0.z = fmaf(d, v.z, a0.z); a0.w = fmaf(d, v.w, a0.w);
    }

    float sx = (a0.x + a1.x) + (a2.x + a3.x);
    float sy = (a0.y + a1.y) + (a2.y + a3.y);
    float sz = (a0.z + a1.z) + (a2.z + a3.z);
    float sw = (a0.w + a1.w) + (a2.w + a3.w);

    const float4 bv = *(const float4*)&bias[lane * 4];
    float4 o;
    o.x = fmaf(dr, sx, bv.x);
    o.y = fmaf(dr, sy, bv.y);
    o.z = fmaf(dr, sz, bv.z);
    o.w = fmaf(dr, sw, bv.w);
    if (RELU) {
        o.x = fmaxf(o.x, 0.f); o.y = fmaxf(o.y, 0.f);
        o.z = fmaxf(o.z, 0.f); o.w = fmaxf(o.w, 0.f);
    }
    ((float4*)out)[(size_t)r * LPR + lane] = o;
}

// ---------------- launch ----------------

extern "C" void kernel_launch(void* const* d_in, const int* in_sizes, int n_in,
                              void* d_out, int out_size, void* d_ws, size_t ws_size,
                              hipStream_t stream) {
    const float* x  = (const float*)d_in[0];
    const int*   ei = (const int*)d_in[1];
    const float* W0 = (const float*)d_in[2];
    const float* b0 = (const float*)d_in[3];
    const float* W1 = (const float*)d_in[4];
    const float* b1 = (const float*)d_in[5];
    const float* W2 = (const float*)d_in[6];
    const float* b2 = (const float*)d_in[7];
    float* out = (float*)d_out;

    const int* row = ei;
    const int* col = ei + NE;

    char* wsp = (char*)d_ws;
    auto alloc = [&](size_t bytes) {
        char* p = wsp;
        wsp += (bytes + 255) & ~(size_t)255;
        return p;
    };
    int*   counts  = (int*)alloc((size_t)NN * 4);
    int*   incl    = (int*)alloc((size_t)NN * 4);
    int*   bsums   = (int*)alloc((size_t)NB * 4);
    int*   offsets = (int*)alloc((size_t)(NN + 1) * 4);
    int*   cursor  = (int*)alloc((size_t)NN * 4);
    float* dinv    = (float*)alloc((size_t)NN * 4);
    int*   csr_col = (int*)alloc((size_t)NE * 4);
    float* Tbuf    = (float*)alloc((size_t)NN * 128 * 4);
    float* Hbuf    = (float*)alloc((size_t)NN * 128 * 4);

    // adjacency build (count/scan), then scatter overlapped with layer-1 GEMM
    zero_i32<<<(NN + 255) / 256, 256, 0, stream>>>(counts, NN);
    count_rows<<<(NE + 255) / 256, 256, 0, stream>>>(row, counts);
    scan_a<<<NB, 1024, 0, stream>>>(counts, incl, bsums);
    scan_c<<<NB, 1024, 0, stream>>>(counts, incl, bsums, offsets, cursor, dinv);

    // fused: scatter blocks first (long pole), gemm1 (raw, no dinv) behind
    const int GB1 = (NN + 31) / 32;   // 3125 gemm blocks (F=128, MB=32)
    fused_scatter_gemm<<<SB + GB1, 256, 0, stream>>>(row, col, cursor, csr_col, x, W0, Tbuf);

    // layer 1: H = relu(A @ Traw + b0), dinv applied in-loop
    spmm_gather<128, true, false><<<(NN + 7) / 8, 256, 0, stream>>>(Tbuf, offsets, csr_col, dinv, b0, Hbuf);
    // layer 2
    gemm128<128><<<(NN + 31) / 32, 256, 0, stream>>>(Hbuf, W1, dinv, Tbuf);
    spmm_gather<128, true, true><<<(NN + 7) / 8, 256, 0, stream>>>(Tbuf, offsets, csr_col, dinv, b1, Hbuf);
    // layer 3 (no relu) -> d_out
    gemm128<64><<<(NN + 63) / 64, 256, 0, stream>>>(Hbuf, W2, dinv, Tbuf);
    spmm_gather<64, false, true><<<(NN + 15) / 16, 256, 0, stream>>>(Tbuf, offsets, csr_col, dinv, b2, out);
}